// Round 13
// baseline (1143.092 us; speedup 1.0000x reference)
//
#include <hip/hip_runtime.h>
#include <cstdint>
#include <cstddef>
#include <cmath>

#define DD 128

typedef short bf16x8 __attribute__((ext_vector_type(8)));
typedef float f32x4 __attribute__((ext_vector_type(4)));

static __device__ __forceinline__ short f2bf(float f){
  union { float f; uint32_t u; } v; v.f = f;
  uint32_t r = v.u + 0x7FFFu + ((v.u >> 16) & 1u);   // RNE
  return (short)(r >> 16);
}
static __device__ __forceinline__ float bf2f(short h){
  union { uint32_t u; float f; } v; v.u = ((uint32_t)(uint16_t)h) << 16;
  return v.f;
}
static __device__ __forceinline__ double shfl_xor_f64(double v, int m){
  long long l = __double_as_longlong(v);
  int lo = (int)(l & 0xffffffffLL);
  int hi = (int)((unsigned long long)l >> 32);
  lo = __shfl_xor(lo, m, 64);
  hi = __shfl_xor(hi, m, 64);
  return __longlong_as_double(((long long)hi << 32) | (unsigned long long)(unsigned int)lo);
}

// async global->LDS, 16B per lane; LDS dest = wave-uniform base + lane*16
static __device__ __forceinline__ void gl_lds16(const float* g, float* l){
  __builtin_amdgcn_global_load_lds(
      (const __attribute__((address_space(1))) void*)g,
      (__attribute__((address_space(3))) void*)l, 16, 0, 0);
}

// ============================================================================
// f32 GEMM, BLAS-identical rounding: each output element is ONE sequential
// fmaf chain over k=0..127 ascending (bit-identical to r12). 256 thr,
// 128x128 tile, 16 rows x 4 cols per thread (64-reg acc — anti-spill).
// Staging via global_load_lds (zero VGPR cost) with k-chunks of 16 and a
// double-buffered LDS pipeline: issue chunk h+1 -> compute chunk h -> barrier.
// Staging geometry correctness-validated in r10/r11 runs (both passed).
// EP 0: Y = acc + bias
// EP 1: Y = ((acc + bias) + T2[src]) + T3[dst]; fused f64 BN stats
// ============================================================================
template<int EP>
__global__ __launch_bounds__(256, 2) void fgemm_k(
    const float* __restrict__ X, const float* __restrict__ W,
    const float* __restrict__ bias, float* __restrict__ Y,
    int M, int nTiles,
    const int* __restrict__ src, const int* __restrict__ dst,
    const float* __restrict__ T2, const float* __restrict__ T3,
    double* __restrict__ eSum, double* __restrict__ eSumSq)
{
  __shared__ float sA[2][128][16];       // 16 KB, linear (gld_lds dest)
  __shared__ float sW[2][16][128];       // 16 KB, linear
  __shared__ double redS[(EP == 1) ? 4 : 1][32][4];   // 4 KB (EP1)
  __shared__ double redQ[(EP == 1) ? 4 : 1][32][4];

  const int tid = threadIdx.x, tx = tid & 31, ty = tid >> 5;
  const int c0 = tx * 4, r0 = ty * 16;
  const int lane = tid & 63, wv = tid >> 6;

  // staging geometry (validated r10/r11): per wave, per chunk:
  //   A: 2 instrs cover rows wv*32..wv*32+31 x 16 k
  //   W: 2 instrs cover k-rows wv*4..wv*4+3 x 128 cols
  const int aRowL = wv * 32 + (lane >> 2);      // + t*16
  const int aCol  = (lane & 3) * 4;
  const int wRowL = wv * 4 + (lane >> 5);       // + t*2
  const int wCol  = (lane & 31) * 4;

  float bias_c[4];
  #pragma unroll
  for (int j = 0; j < 4; ++j) bias_c[j] = bias ? bias[c0 + j] : 0.0f;

  double st_s[4] = {0,0,0,0}, st_q[4] = {0,0,0,0};

  #pragma unroll 1
  for (int tile = blockIdx.x; tile < nTiles; tile += gridDim.x){
    const int rowBase = tile * 128;

    { // issue chunk 0 into buf 0 (k = 0..15)
      #pragma unroll
      for (int t = 0; t < 2; ++t){
        int gr = rowBase + aRowL + t*16; if (gr >= M) gr = M - 1;
        gl_lds16(X + (size_t)gr * DD + aCol, &sA[0][wv*32 + t*16][0]);
        gl_lds16(W + (size_t)(wRowL + t*2) * DD + wCol, &sW[0][wv*4 + t*2][0]);
      }
    }
    __syncthreads();                      // chunk0 DMA complete

    float acc[16][4];
    #pragma unroll
    for (int r = 0; r < 16; ++r)
      #pragma unroll
      for (int j = 0; j < 4; ++j) acc[r][j] = 0.0f;

    int buf = 0;
    #pragma unroll 1
    for (int h = 0; h < 8; ++h){          // k-chunks of 16, ascending
      if (h < 7){                         // issue next chunk into other buffer
        const int hk = (h + 1) * 16;
        #pragma unroll
        for (int t = 0; t < 2; ++t){
          int gr = rowBase + aRowL + t*16; if (gr >= M) gr = M - 1;
          gl_lds16(X + (size_t)gr * DD + hk + aCol, &sA[buf^1][wv*32 + t*16][0]);
          gl_lds16(W + (size_t)(hk + wRowL + t*2) * DD + wCol, &sW[buf^1][wv*4 + t*2][0]);
        }
      }

      #pragma unroll
      for (int q = 0; q < 4; ++q){        // 4 quads of 4 k
        f32x4 b0 = *(const f32x4*)&sW[buf][4*q + 0][c0];
        f32x4 b1 = *(const f32x4*)&sW[buf][4*q + 1][c0];
        f32x4 b2 = *(const f32x4*)&sW[buf][4*q + 2][c0];
        f32x4 b3 = *(const f32x4*)&sW[buf][4*q + 3][c0];
        #pragma unroll
        for (int r = 0; r < 16; ++r){
          f32x4 a = *(const f32x4*)&sA[buf][r0 + r][4*q];
          #pragma unroll
          for (int j = 0; j < 4; ++j){
            float t = acc[r][j];
            t = fmaf(a[0], b0[j], t); t = fmaf(a[1], b1[j], t);
            t = fmaf(a[2], b2[j], t); t = fmaf(a[3], b3[j], t);
            acc[r][j] = t;
          }
        }
      }
      __syncthreads();                    // readers done + next DMA complete
      buf ^= 1;
    }

    // epilogue (r12-identical arithmetic)
    #pragma unroll
    for (int r = 0; r < 16; ++r){
      int row = rowBase + r0 + r;
      if (row < M){
        size_t base = (size_t)row * DD + c0;
        if (EP == 0){
          f32x4 o;
          #pragma unroll
          for (int j = 0; j < 4; ++j) o[j] = acc[r][j] + bias_c[j];
          *(f32x4*)&Y[base] = o;
        } else {
          int s = src[row], d = dst[row];
          f32x4 t2 = *(const f32x4*)&T2[(size_t)s * DD + c0];
          f32x4 t3 = *(const f32x4*)&T3[(size_t)d * DD + c0];
          f32x4 o;
          #pragma unroll
          for (int j = 0; j < 4; ++j){
            o[j] = ((acc[r][j] + bias_c[j]) + t2[j]) + t3[j];   // ref add order
            st_s[j] += (double)o[j];
            st_q[j] += (double)o[j] * (double)o[j];
          }
          *(f32x4*)&Y[base] = o;
        }
      }
    }
  }

  if (EP == 1){
    #pragma unroll
    for (int j = 0; j < 4; ++j){
      st_s[j] += shfl_xor_f64(st_s[j], 32);
      st_q[j] += shfl_xor_f64(st_q[j], 32);
    }
    if (lane < 32){
      #pragma unroll
      for (int j = 0; j < 4; ++j){ redS[wv][lane][j] = st_s[j]; redQ[wv][lane][j] = st_q[j]; }
    }
    __syncthreads();
    if (tid < 128){
      int txx = tid >> 2, j = tid & 3;
      double s = 0.0, q = 0.0;
      #pragma unroll
      for (int w = 0; w < 4; ++w){ s += redS[w][txx][j]; q += redQ[w][txx][j]; }
      atomicAdd(&eSum[txx*4 + j], s);
      atomicAdd(&eSumSq[txx*4 + j], q);
    }
  }
}

// ============================================================================
// Merged sigma GEMM with fused e_new construction (r12-proven, UNCHANGED).
//   en = e_emb + relu(bn(pre_e)) -> stored to eNew ; sA = sigmoid(en)
//   sigma = sA @ Weta (single sequential fmaf chain per element)
// sigmaOut may alias eEmb (write-after-read per tile, barrier-ordered);
// eNew may alias preE. Requires M % 128 == 0 (NE = 400000 = 3125*128).
// ============================================================================
__global__ __launch_bounds__(256, 2) void psgemm_k(
    const float* __restrict__ preE, const float* __restrict__ eEmb,
    const float* __restrict__ Weta,
    float* __restrict__ eNew, float* __restrict__ sigmaOut,
    const float* __restrict__ mF, const float* __restrict__ rF,
    const float* __restrict__ gF, const float* __restrict__ bF,
    int M, int nTiles)
{
  __shared__ float sA[128][36];          // 18 KB
  __shared__ float sW[32][128];          // 16 KB
  __shared__ float sBN[4][128];          // 2 KB: m, r, gamma, beta

  const int tid = threadIdx.x, tx = tid & 31, ty = tid >> 5;
  const int c0 = tx * 4, r0 = ty * 16;
  const int sa_r = tid >> 1, sa_k = (tid & 1) * 16;
  const int sw_k = tid >> 3, sw_c = (tid & 7) * 16;

  if (tid < 128){
    sBN[0][tid] = mF[tid]; sBN[1][tid] = rF[tid];
    sBN[2][tid] = gF[tid]; sBN[3][tid] = bF[tid];
  }
  __syncthreads();

  #pragma unroll 1
  for (int tile = blockIdx.x; tile < nTiles; tile += gridDim.x){
    const int rowBase = tile * 128;
    const int ar = rowBase + sa_r;

    float acc[16][4];
    #pragma unroll
    for (int r = 0; r < 16; ++r)
      #pragma unroll
      for (int j = 0; j < 4; ++j) acc[r][j] = 0.0f;

    #pragma unroll 1
    for (int h = 0; h < 4; ++h){         // k-chunks of 32, ascending
      { // stage sW chunk
        const float* wp = Weta + (size_t)(h*32 + sw_k) * DD + sw_c;
        #pragma unroll
        for (int i = 0; i < 4; ++i)
          *(f32x4*)&sW[sw_k][sw_c + i*4] = *(const f32x4*)(wp + i*4);
      }
      { // fused stage: en = e_emb + relu(bn(pre_e)); store e_new; sA = sigmoid(en)
        int gcb = h*32 + sa_k;
        const float* pp = preE + (size_t)ar * DD + gcb;
        const float* ep = eEmb + (size_t)ar * DD + gcb;
        float* np = eNew + (size_t)ar * DD + gcb;
        #pragma unroll
        for (int i = 0; i < 4; ++i){
          f32x4 pe = *(const f32x4*)(pp + i*4);
          f32x4 em = *(const f32x4*)(ep + i*4);
          f32x4 mm = *(const f32x4*)&sBN[0][gcb + i*4];
          f32x4 rr = *(const f32x4*)&sBN[1][gcb + i*4];
          f32x4 gg = *(const f32x4*)&sBN[2][gcb + i*4];
          f32x4 bb = *(const f32x4*)&sBN[3][gcb + i*4];
          f32x4 en, sg;
          #pragma unroll
          for (int j = 0; j < 4; ++j){
            float xm  = pe[j] - mm[j];
            float t1  = xm * rr[j];
            float t2v = t1 * gg[j];
            float t3v = t2v + bb[j];
            float t = fmaxf(t3v, 0.0f);
            en[j] = em[j] + t;                     // e_new (r12-identical chain)
            sg[j] = 1.0f / (1.0f + expf(-en[j]));
          }
          *(f32x4*)(np + i*4) = en;
          *(f32x4*)&sA[sa_r][sa_k + i*4] = sg;
        }
      }
      __syncthreads();

      #pragma unroll
      for (int q = 0; q < 8; ++q){
        f32x4 b0 = *(const f32x4*)&sW[4*q + 0][c0];
        f32x4 b1 = *(const f32x4*)&sW[4*q + 1][c0];
        f32x4 b2 = *(const f32x4*)&sW[4*q + 2][c0];
        f32x4 b3 = *(const f32x4*)&sW[4*q + 3][c0];
        #pragma unroll
        for (int r = 0; r < 16; ++r){
          f32x4 a = *(const f32x4*)&sA[r0 + r][4*q];
          #pragma unroll
          for (int j = 0; j < 4; ++j){
            float t = acc[r][j];
            t = fmaf(a[0], b0[j], t); t = fmaf(a[1], b1[j], t);
            t = fmaf(a[2], b2[j], t); t = fmaf(a[3], b3[j], t);
            acc[r][j] = t;
          }
        }
      }
      __syncthreads();
    }

    #pragma unroll
    for (int r = 0; r < 16; ++r){
      int row = rowBase + r0 + r;
      f32x4 o;
      #pragma unroll
      for (int j = 0; j < 4; ++j) o[j] = acc[r][j];
      *(f32x4*)&sigmaOut[(size_t)row * DD + c0] = o;
    }
  }
}

// ---------------- CSR build: bucket edges by dst ----------------
__global__ void hist_k(const int* __restrict__ dst, int NE, int* __restrict__ counts){
  int i = blockIdx.x * blockDim.x + threadIdx.x;
  if (i < NE) atomicAdd(&counts[dst[i]], 1);
}

__global__ __launch_bounds__(1024, 1) void scan_k(const int* __restrict__ counts, int NN,
                                                  int* __restrict__ rowStart, int* __restrict__ cursor){
  __shared__ int part[1024];
  const int T = 1024, t = threadIdx.x;
  const int chunk = (NN + T - 1) / T;
  const int lo = t * chunk;
  const int hi = (lo + chunk < NN) ? lo + chunk : NN;
  int s = 0;
  for (int i = lo; i < hi; ++i) s += counts[i];
  part[t] = s;
  __syncthreads();
  for (int off = 1; off < T; off <<= 1){
    int v = (t >= off) ? part[t - off] : 0;
    __syncthreads();
    part[t] += v;
    __syncthreads();
  }
  int run = (t == 0) ? 0 : part[t - 1];
  for (int i = lo; i < hi; ++i){ rowStart[i] = run; cursor[i] = run; run += counts[i]; }
  if (t == T - 1) rowStart[NN] = run;
}

__global__ void place_k(const int* __restrict__ dst, int NE,
                        int* __restrict__ cursor, int* __restrict__ edgeIdx){
  int i = blockIdx.x * blockDim.x + threadIdx.x;
  if (i < NE){ int p = atomicAdd(&cursor[dst[i]], 1); edgeIdx[p] = i; }
}

// ---------------- gather-reduce: den/num from dense sigma, bucket order ------
__global__ __launch_bounds__(256, 4) void gather_k(
    const float* __restrict__ sigma, const float* __restrict__ Vh,
    const int* __restrict__ rowStart, const int* __restrict__ edgeIdx,
    const int* __restrict__ srcArr,
    const float* __restrict__ Uh, float* __restrict__ preH, int NN)
{
  const int lane = threadIdx.x & 63, wv = threadIdx.x >> 6;
  for (int node = blockIdx.x * 4 + wv; node < NN; node += gridDim.x * 4){
    const int beg = rowStart[node], end = rowStart[node + 1];
    float den0 = 0.f, den1 = 0.f, num0 = 0.f, num1 = 0.f;
    for (int eb = beg; eb < end; eb += 8){
      const int nE = end - eb;
      float sg0[8], sg1[8], vh0[8], vh1[8];
      #pragma unroll
      for (int q = 0; q < 8; ++q){
        if (q < nE){
          int eid = edgeIdx[eb + q];
          int s = srcArr[eid];
          sg0[q] = sigma[(size_t)eid * DD + lane];
          sg1[q] = sigma[(size_t)eid * DD + 64 + lane];
          vh0[q] = Vh[(size_t)s * DD + lane];
          vh1[q] = Vh[(size_t)s * DD + 64 + lane];
        } else { sg0[q] = 0.f; sg1[q] = 0.f; vh0[q] = 0.f; vh1[q] = 0.f; }
      }
      #pragma unroll
      for (int q = 0; q < 8; ++q){
        den0 += sg0[q]; den1 += sg1[q];
        num0 = fmaf(sg0[q], vh0[q], num0);
        num1 = fmaf(sg1[q], vh1[q], num1);
      }
    }
    const size_t b = (size_t)node * DD;
    preH[b + lane]      = Uh[b + lane]      + num0 / (den0 + 1e-5f);
    preH[b + 64 + lane] = Uh[b + 64 + lane] + num1 / (den1 + 1e-5f);
  }
}

// e-BN params: f64 stats -> f32 mean and f32 rsqrt
__global__ void finalizeE_k(const double* __restrict__ sum, const double* __restrict__ sumsq,
                            double M, float* __restrict__ mF, float* __restrict__ rF)
{
  int c = threadIdx.x;
  double m = sum[c] / M;
  double v = sumsq[c] / M - m * m;
  float vf = (float)v;
  mF[c] = (float)m;
  rF[c] = 1.0f / sqrtf(vf + 1e-5f);
}

// column stats (f32 in, f64 accum)
__global__ void stats64_k(const float* __restrict__ X, int M,
                          double* __restrict__ sum, double* __restrict__ sumsq)
{
  const int col = threadIdx.x & 127;
  const int half = threadIdx.x >> 7;
  double s = 0.0, q = 0.0;
  for (int r = blockIdx.x * 2 + half; r < M; r += gridDim.x * 2){
    double v = (double)X[(size_t)r * DD + col];
    s += v; q += v * v;
  }
  __shared__ double sS[256], sQ[256];
  sS[threadIdx.x] = s; sQ[threadIdx.x] = q;
  __syncthreads();
  if (half == 0){
    atomicAdd(&sum[col],   sS[col] + sS[col + 128]);
    atomicAdd(&sumsq[col], sQ[col] + sQ[col + 128]);
  }
}

__global__ void finalize64_k(const double* __restrict__ sum, const double* __restrict__ sumsq,
                             double M, const float* __restrict__ gamma, const float* __restrict__ beta,
                             double* __restrict__ scale, double* __restrict__ shift)
{
  int c = threadIdx.x;
  double m = sum[c] / M;
  double var = sumsq[c] / M - m * m;
  double sc = (double)gamma[c] / sqrt(var + 1e-5);
  scale[c] = sc;
  shift[c] = (double)beta[c] - m * sc;
}

// ---------------- split-bf16 MFMA GEMM: h_new = h@Wemb_n + relu(bn(pre_h)) ----
__global__ __launch_bounds__(256, 2) void hfinal_mfma_k(
    const float* __restrict__ X, const float* __restrict__ W,
    float* __restrict__ Y, int M, int rowTiles,
    const float* __restrict__ preH,
    const double* __restrict__ hSc, const double* __restrict__ hSh)
{
  const int tid = threadIdx.x;
  const int lane = tid & 63;
  const int wv = tid >> 6;
  const int l15 = lane & 15;
  const int lg = lane >> 4;
  const int colBase = blockIdx.y * 64;

  __shared__ short sW[2][64][136];
  for (int t = tid; t < 64 * 128; t += 256){
    int k = t >> 6, nl = t & 63;
    float w = W[k * DD + colBase + nl];
    short hi = f2bf(w);
    sW[0][nl][k] = hi;
    sW[1][nl][k] = f2bf(w - bf2f(hi));
  }
  __syncthreads();

  bf16x8 Bhi[4][4], Blo[4][4];
  #pragma unroll
  for (int ct = 0; ct < 4; ++ct)
    #pragma unroll
    for (int ks = 0; ks < 4; ++ks){
      Bhi[ct][ks] = *(const bf16x8*)&sW[0][ct*16 + l15][ks*32 + lg*8];
      Blo[ct][ks] = *(const bf16x8*)&sW[1][ct*16 + l15][ks*32 + lg*8];
    }

  for (int rt = blockIdx.x; rt < rowTiles; rt += gridDim.x){
    int arow = rt * 64 + wv * 16 + l15;
    if (arow >= M) arow = M - 1;
    const f32x4* xr = (const f32x4*)(X + (size_t)arow * DD);

    bf16x8 Ahi[4], Alo[4];
    #pragma unroll
    for (int ks = 0; ks < 4; ++ks){
      f32x4 a0 = xr[ks*8 + lg*2];
      f32x4 a1 = xr[ks*8 + lg*2 + 1];
      float av[8];
      #pragma unroll
      for (int j = 0; j < 4; ++j){ av[j] = a0[j]; av[4+j] = a1[j]; }
      #pragma unroll
      for (int j = 0; j < 8; ++j){
        short hi = f2bf(av[j]);
        Ahi[ks][j] = hi;
        Alo[ks][j] = f2bf(av[j] - bf2f(hi));
      }
    }

    f32x4 acc[4];
    #pragma unroll
    for (int ct = 0; ct < 4; ++ct) acc[ct] = (f32x4){0.f, 0.f, 0.f, 0.f};
    #pragma unroll
    for (int ct = 0; ct < 4; ++ct)
      #pragma unroll
      for (int ks = 0; ks < 4; ++ks){
        acc[ct] = __builtin_amdgcn_mfma_f32_16x16x32_bf16(Ahi[ks], Bhi[ct][ks], acc[ct], 0, 0, 0);
        acc[ct] = __builtin_amdgcn_mfma_f32_16x16x32_bf16(Ahi[ks], Blo[ct][ks], acc[ct], 0, 0, 0);
        acc[ct] = __builtin_amdgcn_mfma_f32_16x16x32_bf16(Alo[ks], Bhi[ct][ks], acc[ct], 0, 0, 0);
      }

    const int r0 = rt * 64 + wv * 16 + lg * 4;
    #pragma unroll
    for (int reg = 0; reg < 4; ++reg){
      int r = r0 + reg;
      if (r < M){
        #pragma unroll
        for (int ct = 0; ct < 4; ++ct){
          int c = colBase + ct*16 + l15;
          double t = (double)preH[(size_t)r * DD + c] * hSc[c] + hSh[c];
          float tv = t > 0.0 ? (float)t : 0.0f;
          Y[(size_t)r * DD + c] = acc[ct][reg] + tv;
        }
      }
    }
  }
}

extern "C" void kernel_launch(void* const* d_in, const int* in_sizes, int n_in,
                              void* d_out, int out_size, void* d_ws, size_t ws_size,
                              hipStream_t stream)
{
  const float* h  = (const float*)d_in[0];
  const float* e  = (const float*)d_in[1];
  const int* src  = (const int*)d_in[2];
  const int* dst  = (const int*)d_in[3];
  const float* Wemb_n   = (const float*)d_in[4];
  const float* Wemb_e   = (const float*)d_in[5];
  const float* Wemb_eta = (const float*)d_in[6];
  const float* Uw  = (const float*)d_in[7];  const float* Ub  = (const float*)d_in[8];
  const float* Vw  = (const float*)d_in[9];  const float* Vb  = (const float*)d_in[10];
  const float* W1w = (const float*)d_in[11]; const float* W1b = (const float*)d_in[12];
  const float* W2w = (const float*)d_in[13]; const float* W2b = (const float*)d_in[14];
  const float* W3w = (const float*)d_in[15]; const float* W3b = (const float*)d_in[16];
  const float* h_gamma = (const float*)d_in[17]; const float* h_beta = (const float*)d_in[18];
  const float* e_gamma = (const float*)d_in[19]; const float* e_beta = (const float*)d_in[20];

  const int NN = in_sizes[0] / DD;   // 50000
  const int NE = in_sizes[2];        // 400000

  // workspace: W2h | W3h | Vh | embSig (e_emb -> sigma, shared) | stats | mF,rF | CSR
  char* wsp = (char*)d_ws;
  float* W2h    = (float*)wsp;  wsp += (size_t)NN * DD * sizeof(float);
  float* W3h    = (float*)wsp;  wsp += (size_t)NN * DD * sizeof(float);
  float* Vh     = (float*)wsp;  wsp += (size_t)NN * DD * sizeof(float);
  float* embSig = (float*)wsp;  wsp += (size_t)NE * DD * sizeof(float);
  double* stats = (double*)wsp; wsp += 6 * DD * sizeof(double);
  double* eSum = stats;        double* eSumSq = stats + DD;
  double* hSum = stats + 2*DD; double* hSumSq = stats + 3*DD;
  double* hScale = stats + 4*DD; double* hShift = stats + 5*DD;
  float* mF = (float*)wsp;   wsp += DD * sizeof(float);
  float* rF = (float*)wsp;   wsp += DD * sizeof(float);
  int* counts   = (int*)wsp; wsp += (size_t)NN * sizeof(int);
  int* rowStart = (int*)wsp; wsp += ((size_t)NN + 1) * sizeof(int);
  int* cursor   = (int*)wsp; wsp += (size_t)NN * sizeof(int);
  int* edgeIdx  = (int*)wsp; wsp += (size_t)NE * sizeof(int);

  float* h_new_out = (float*)d_out;                    // Uh -> pre_h -> h_new
  float* e_out     = (float*)d_out + (size_t)NN * DD;  // pre_e -> e_new

  const int tN = (NN + 127) / 128;    // 391
  const int tE = (NE + 127) / 128;    // 3125 (exact)
  const int rtN64 = (NN + 63) / 64;
  dim3 blk256(256);

  hipMemsetAsync(stats, 0, (size_t)4 * DD * sizeof(double), stream);
  hipMemsetAsync(counts, 0, (size_t)NN * sizeof(int), stream);

  // CSR build
  hist_k<<<(NE + 255) / 256, blk256, 0, stream>>>(dst, NE, counts);
  scan_k<<<1, 1024, 0, stream>>>(counts, NN, rowStart, cursor);
  place_k<<<(NE + 255) / 256, blk256, 0, stream>>>(dst, NE, cursor, edgeIdx);

  // node GEMMs (f32 BLAS-order, async-staged)
  fgemm_k<0><<<tN, blk256, 0, stream>>>(h, Uw, Ub, h_new_out, NN, tN,
      nullptr, nullptr, nullptr, nullptr, nullptr, nullptr);
  fgemm_k<0><<<tN, blk256, 0, stream>>>(h, Vw, Vb, Vh, NN, tN,
      nullptr, nullptr, nullptr, nullptr, nullptr, nullptr);
  fgemm_k<0><<<tN, blk256, 0, stream>>>(h, W2w, W2b, W2h, NN, tN,
      nullptr, nullptr, nullptr, nullptr, nullptr, nullptr);
  fgemm_k<0><<<tN, blk256, 0, stream>>>(h, W3w, W3b, W3h, NN, tN,
      nullptr, nullptr, nullptr, nullptr, nullptr, nullptr);

  // pre_e = ((e@W1 + W1b) + W2h[src]) + W3h[dst] -> e_out; fused f64 stats
  fgemm_k<1><<<1024, blk256, 0, stream>>>(e, W1w, W1b, e_out, NE, tE,
      src, dst, W2h, W3h, eSum, eSumSq);

  finalizeE_k<<<1, 128, 0, stream>>>(eSum, eSumSq, (double)NE, mF, rF);

  // e_emb = e @ Wemb_e -> embSig
  fgemm_k<0><<<1024, blk256, 0, stream>>>(e, Wemb_e, nullptr, embSig, NE, tE,
      nullptr, nullptr, nullptr, nullptr, nullptr, nullptr);

  // fused: e_new = e_emb + relu(bn(pre_e)) (-> e_out), sigma = sigmoid(e_new)@Weta
  // sigma written over embSig (write-after-read per tile)
  psgemm_k<<<1024, blk256, 0, stream>>>(e_out, embSig, Wemb_eta, e_out, embSig,
      mF, rF, e_gamma, e_beta, NE, tE);

  // bucket-order gather-reduce: pre_h = Uh + num/(den+1e-5)  (in place over d_out)
  gather_k<<<(NN + 3) / 4, blk256, 0, stream>>>(embSig, Vh, rowStart, edgeIdx, src,
      h_new_out, h_new_out, NN);

  stats64_k<<<512, blk256, 0, stream>>>(h_new_out, NN, hSum, hSumSq);
  finalize64_k<<<1, 128, 0, stream>>>(hSum, hSumSq, (double)NN, h_gamma, h_beta, hScale, hShift);

  // h_new = h@Wemb_n + relu(bn(pre_h))  (MFMA; post-division path)
  hfinal_mfma_k<<<dim3(rtN64, 2), blk256, 0, stream>>>(h, Wemb_n, h_new_out, NN, rtN64,
      h_new_out, hScale, hShift);
}

// Round 14
// 1089.260 us; speedup vs baseline: 1.0494x; 1.0494x over previous
//
#include <hip/hip_runtime.h>
#include <cstdint>
#include <cstddef>
#include <cmath>

#define DD 128

typedef short bf16x8 __attribute__((ext_vector_type(8)));
typedef float f32x4 __attribute__((ext_vector_type(4)));

static __device__ __forceinline__ short f2bf(float f){
  union { float f; uint32_t u; } v; v.f = f;
  uint32_t r = v.u + 0x7FFFu + ((v.u >> 16) & 1u);   // RNE
  return (short)(r >> 16);
}
static __device__ __forceinline__ float bf2f(short h){
  union { uint32_t u; float f; } v; v.u = ((uint32_t)(uint16_t)h) << 16;
  return v.f;
}
static __device__ __forceinline__ double shfl_xor_f64(double v, int m){
  long long l = __double_as_longlong(v);
  int lo = (int)(l & 0xffffffffLL);
  int hi = (int)((unsigned long long)l >> 32);
  lo = __shfl_xor(lo, m, 64);
  hi = __shfl_xor(hi, m, 64);
  return __longlong_as_double(((long long)hi << 32) | (unsigned long long)(unsigned int)lo);
}

// ============================================================================
// f32 GEMM, BLAS-identical rounding (r12-proven, sync staging): each output
// element is ONE sequential fmaf chain over k=0..127 ascending. 256 thr,
// 128x128 tile, 16 rows x 4 cols per thread (64-reg acc, ~100 VGPR: safe).
// EP 1: Y = ((acc + bias) + T2[src]) + T3[dst]; fused f64 BN stats
// ============================================================================
__global__ __launch_bounds__(256, 2) void fgemmE1_k(
    const float* __restrict__ X, const float* __restrict__ W,
    const float* __restrict__ bias, float* __restrict__ Y,
    int M, int nTiles,
    const int* __restrict__ src, const int* __restrict__ dst,
    const float* __restrict__ T2, const float* __restrict__ T3,
    double* __restrict__ eSum, double* __restrict__ eSumSq)
{
  __shared__ float sA[128][36];
  __shared__ float sW[32][128];
  __shared__ double redS[4][32][4];
  __shared__ double redQ[4][32][4];

  const int tid = threadIdx.x, tx = tid & 31, ty = tid >> 5;
  const int c0 = tx * 4, r0 = ty * 16;
  const int lane = tid & 63, wv = tid >> 6;
  const int sa_r = tid >> 1, sa_k = (tid & 1) * 16;
  const int sw_k = tid >> 3, sw_c = (tid & 7) * 16;

  float bias_c[4];
  #pragma unroll
  for (int j = 0; j < 4; ++j) bias_c[j] = bias[c0 + j];

  double st_s[4] = {0,0,0,0}, st_q[4] = {0,0,0,0};

  #pragma unroll 1
  for (int tile = blockIdx.x; tile < nTiles; tile += gridDim.x){
    const int rowBase = tile * 128;
    float acc[16][4];
    #pragma unroll
    for (int r = 0; r < 16; ++r)
      #pragma unroll
      for (int j = 0; j < 4; ++j) acc[r][j] = 0.0f;

    #pragma unroll 1
    for (int h = 0; h < 4; ++h){
      {
        const float* wp = W + (size_t)(h*32 + sw_k) * DD + sw_c;
        #pragma unroll
        for (int i = 0; i < 4; ++i)
          *(f32x4*)&sW[sw_k][sw_c + i*4] = *(const f32x4*)(wp + i*4);
      }
      {
        int ar = rowBase + sa_r; if (ar >= M) ar = M - 1;
        const float* xp = X + (size_t)ar * DD + h*32 + sa_k;
        #pragma unroll
        for (int i = 0; i < 4; ++i)
          *(f32x4*)&sA[sa_r][sa_k + i*4] = *(const f32x4*)(xp + i*4);
      }
      __syncthreads();

      #pragma unroll
      for (int q = 0; q < 8; ++q){
        f32x4 b0 = *(const f32x4*)&sW[4*q + 0][c0];
        f32x4 b1 = *(const f32x4*)&sW[4*q + 1][c0];
        f32x4 b2 = *(const f32x4*)&sW[4*q + 2][c0];
        f32x4 b3 = *(const f32x4*)&sW[4*q + 3][c0];
        #pragma unroll
        for (int r = 0; r < 16; ++r){
          f32x4 a = *(const f32x4*)&sA[r0 + r][4*q];
          #pragma unroll
          for (int j = 0; j < 4; ++j){
            float t = acc[r][j];
            t = fmaf(a[0], b0[j], t); t = fmaf(a[1], b1[j], t);
            t = fmaf(a[2], b2[j], t); t = fmaf(a[3], b3[j], t);
            acc[r][j] = t;
          }
        }
      }
      __syncthreads();
    }

    #pragma unroll
    for (int r = 0; r < 16; ++r){
      int row = rowBase + r0 + r;
      if (row < M){
        size_t base = (size_t)row * DD + c0;
        int s = src[row], d = dst[row];
        f32x4 t2 = *(const f32x4*)&T2[(size_t)s * DD + c0];
        f32x4 t3 = *(const f32x4*)&T3[(size_t)d * DD + c0];
        f32x4 o;
        #pragma unroll
        for (int j = 0; j < 4; ++j){
          o[j] = ((acc[r][j] + bias_c[j]) + t2[j]) + t3[j];   // ref add order
          st_s[j] += (double)o[j];
          st_q[j] += (double)o[j] * (double)o[j];
        }
        *(f32x4*)&Y[base] = o;
      }
    }
  }

  #pragma unroll
  for (int j = 0; j < 4; ++j){
    st_s[j] += shfl_xor_f64(st_s[j], 32);
    st_q[j] += shfl_xor_f64(st_q[j], 32);
  }
  if (lane < 32){
    #pragma unroll
    for (int j = 0; j < 4; ++j){ redS[wv][lane][j] = st_s[j]; redQ[wv][lane][j] = st_q[j]; }
  }
  __syncthreads();
  if (tid < 128){
    int txx = tid >> 2, j = tid & 3;
    double s = 0.0, q = 0.0;
    #pragma unroll
    for (int w = 0; w < 4; ++w){ s += redS[w][txx][j]; q += redQ[w][txx][j]; }
    atomicAdd(&eSum[txx*4 + j], s);
    atomicAdd(&eSumSq[txx*4 + j], q);
  }
}

// ============================================================================
// EP0 GEMM (r12 body): Y = X@W + b. Used for e_emb (single weight set).
// ============================================================================
__global__ __launch_bounds__(256, 2) void fgemm0_k(
    const float* __restrict__ X, const float* __restrict__ W,
    const float* __restrict__ bias, float* __restrict__ Y,
    int M, int nTiles)
{
  __shared__ float sA[128][36];
  __shared__ float sW[32][128];

  const int tid = threadIdx.x, tx = tid & 31, ty = tid >> 5;
  const int c0 = tx * 4, r0 = ty * 16;
  const int sa_r = tid >> 1, sa_k = (tid & 1) * 16;
  const int sw_k = tid >> 3, sw_c = (tid & 7) * 16;

  float bias_c[4];
  #pragma unroll
  for (int j = 0; j < 4; ++j) bias_c[j] = bias ? bias[c0 + j] : 0.0f;

  #pragma unroll 1
  for (int tile = blockIdx.x; tile < nTiles; tile += gridDim.x){
    const int rowBase = tile * 128;
    float acc[16][4];
    #pragma unroll
    for (int r = 0; r < 16; ++r)
      #pragma unroll
      for (int j = 0; j < 4; ++j) acc[r][j] = 0.0f;

    #pragma unroll 1
    for (int h = 0; h < 4; ++h){
      {
        const float* wp = W + (size_t)(h*32 + sw_k) * DD + sw_c;
        #pragma unroll
        for (int i = 0; i < 4; ++i)
          *(f32x4*)&sW[sw_k][sw_c + i*4] = *(const f32x4*)(wp + i*4);
      }
      {
        int ar = rowBase + sa_r; if (ar >= M) ar = M - 1;
        const float* xp = X + (size_t)ar * DD + h*32 + sa_k;
        #pragma unroll
        for (int i = 0; i < 4; ++i)
          *(f32x4*)&sA[sa_r][sa_k + i*4] = *(const f32x4*)(xp + i*4);
      }
      __syncthreads();

      #pragma unroll
      for (int q = 0; q < 8; ++q){
        f32x4 b0 = *(const f32x4*)&sW[4*q + 0][c0];
        f32x4 b1 = *(const f32x4*)&sW[4*q + 1][c0];
        f32x4 b2 = *(const f32x4*)&sW[4*q + 2][c0];
        f32x4 b3 = *(const f32x4*)&sW[4*q + 3][c0];
        #pragma unroll
        for (int r = 0; r < 16; ++r){
          f32x4 a = *(const f32x4*)&sA[r0 + r][4*q];
          #pragma unroll
          for (int j = 0; j < 4; ++j){
            float t = acc[r][j];
            t = fmaf(a[0], b0[j], t); t = fmaf(a[1], b1[j], t);
            t = fmaf(a[2], b2[j], t); t = fmaf(a[3], b3[j], t);
            acc[r][j] = t;
          }
        }
      }
      __syncthreads();
    }

    #pragma unroll
    for (int r = 0; r < 16; ++r){
      int row = rowBase + r0 + r;
      if (row < M){
        f32x4 o;
        #pragma unroll
        for (int j = 0; j < 4; ++j) o[j] = acc[r][j] + bias_c[j];
        *(f32x4*)&Y[(size_t)row * DD + c0] = o;
      }
    }
  }
}

// ============================================================================
// Merged node GEMMs: blockIdx.y in 0..3 selects {U, V, W2, W3} weight/bias/out.
// Body identical to fgemm0_k (bit-identical chains). One launch, 4x fill.
// ============================================================================
__global__ __launch_bounds__(256, 2) void node4_k(
    const float* __restrict__ X,
    const float* __restrict__ W0, const float* __restrict__ b0v, float* __restrict__ Y0,
    const float* __restrict__ W1, const float* __restrict__ b1v, float* __restrict__ Y1,
    const float* __restrict__ W2, const float* __restrict__ b2v, float* __restrict__ Y2,
    const float* __restrict__ W3, const float* __restrict__ b3v, float* __restrict__ Y3,
    int M, int nTiles)
{
  __shared__ float sA[128][36];
  __shared__ float sW[32][128];

  const int tid = threadIdx.x, tx = tid & 31, ty = tid >> 5;
  const int c0 = tx * 4, r0 = ty * 16;
  const int sa_r = tid >> 1, sa_k = (tid & 1) * 16;
  const int sw_k = tid >> 3, sw_c = (tid & 7) * 16;

  const float* W = W0; const float* bias = b0v; float* Y = Y0;
  if (blockIdx.y == 1){ W = W1; bias = b1v; Y = Y1; }
  else if (blockIdx.y == 2){ W = W2; bias = b2v; Y = Y2; }
  else if (blockIdx.y == 3){ W = W3; bias = b3v; Y = Y3; }

  float bias_c[4];
  #pragma unroll
  for (int j = 0; j < 4; ++j) bias_c[j] = bias[c0 + j];

  #pragma unroll 1
  for (int tile = blockIdx.x; tile < nTiles; tile += gridDim.x){
    const int rowBase = tile * 128;
    float acc[16][4];
    #pragma unroll
    for (int r = 0; r < 16; ++r)
      #pragma unroll
      for (int j = 0; j < 4; ++j) acc[r][j] = 0.0f;

    #pragma unroll 1
    for (int h = 0; h < 4; ++h){
      {
        const float* wp = W + (size_t)(h*32 + sw_k) * DD + sw_c;
        #pragma unroll
        for (int i = 0; i < 4; ++i)
          *(f32x4*)&sW[sw_k][sw_c + i*4] = *(const f32x4*)(wp + i*4);
      }
      {
        int ar = rowBase + sa_r; if (ar >= M) ar = M - 1;
        const float* xp = X + (size_t)ar * DD + h*32 + sa_k;
        #pragma unroll
        for (int i = 0; i < 4; ++i)
          *(f32x4*)&sA[sa_r][sa_k + i*4] = *(const f32x4*)(xp + i*4);
      }
      __syncthreads();

      #pragma unroll
      for (int q = 0; q < 8; ++q){
        f32x4 b0 = *(const f32x4*)&sW[4*q + 0][c0];
        f32x4 b1 = *(const f32x4*)&sW[4*q + 1][c0];
        f32x4 b2 = *(const f32x4*)&sW[4*q + 2][c0];
        f32x4 b3 = *(const f32x4*)&sW[4*q + 3][c0];
        #pragma unroll
        for (int r = 0; r < 16; ++r){
          f32x4 a = *(const f32x4*)&sA[r0 + r][4*q];
          #pragma unroll
          for (int j = 0; j < 4; ++j){
            float t = acc[r][j];
            t = fmaf(a[0], b0[j], t); t = fmaf(a[1], b1[j], t);
            t = fmaf(a[2], b2[j], t); t = fmaf(a[3], b3[j], t);
            acc[r][j] = t;
          }
        }
      }
      __syncthreads();
    }

    #pragma unroll
    for (int r = 0; r < 16; ++r){
      int row = rowBase + r0 + r;
      if (row < M){
        f32x4 o;
        #pragma unroll
        for (int j = 0; j < 4; ++j) o[j] = acc[r][j] + bias_c[j];
        *(f32x4*)&Y[(size_t)row * DD + c0] = o;
      }
    }
  }
}

// ============================================================================
// Merged sigma GEMM with fused e_new construction (r12-proven, UNCHANGED).
// ============================================================================
__global__ __launch_bounds__(256, 2) void psgemm_k(
    const float* __restrict__ preE, const float* __restrict__ eEmb,
    const float* __restrict__ Weta,
    float* __restrict__ eNew, float* __restrict__ sigmaOut,
    const float* __restrict__ mF, const float* __restrict__ rF,
    const float* __restrict__ gF, const float* __restrict__ bF,
    int M, int nTiles)
{
  __shared__ float sA[128][36];
  __shared__ float sW[32][128];
  __shared__ float sBN[4][128];

  const int tid = threadIdx.x, tx = tid & 31, ty = tid >> 5;
  const int c0 = tx * 4, r0 = ty * 16;
  const int sa_r = tid >> 1, sa_k = (tid & 1) * 16;
  const int sw_k = tid >> 3, sw_c = (tid & 7) * 16;

  if (tid < 128){
    sBN[0][tid] = mF[tid]; sBN[1][tid] = rF[tid];
    sBN[2][tid] = gF[tid]; sBN[3][tid] = bF[tid];
  }
  __syncthreads();

  #pragma unroll 1
  for (int tile = blockIdx.x; tile < nTiles; tile += gridDim.x){
    const int rowBase = tile * 128;
    const int ar = rowBase + sa_r;

    float acc[16][4];
    #pragma unroll
    for (int r = 0; r < 16; ++r)
      #pragma unroll
      for (int j = 0; j < 4; ++j) acc[r][j] = 0.0f;

    #pragma unroll 1
    for (int h = 0; h < 4; ++h){
      {
        const float* wp = Weta + (size_t)(h*32 + sw_k) * DD + sw_c;
        #pragma unroll
        for (int i = 0; i < 4; ++i)
          *(f32x4*)&sW[sw_k][sw_c + i*4] = *(const f32x4*)(wp + i*4);
      }
      {
        int gcb = h*32 + sa_k;
        const float* pp = preE + (size_t)ar * DD + gcb;
        const float* ep = eEmb + (size_t)ar * DD + gcb;
        float* np = eNew + (size_t)ar * DD + gcb;
        #pragma unroll
        for (int i = 0; i < 4; ++i){
          f32x4 pe = *(const f32x4*)(pp + i*4);
          f32x4 em = *(const f32x4*)(ep + i*4);
          f32x4 mm = *(const f32x4*)&sBN[0][gcb + i*4];
          f32x4 rr = *(const f32x4*)&sBN[1][gcb + i*4];
          f32x4 gg = *(const f32x4*)&sBN[2][gcb + i*4];
          f32x4 bb = *(const f32x4*)&sBN[3][gcb + i*4];
          f32x4 en, sg;
          #pragma unroll
          for (int j = 0; j < 4; ++j){
            float xm  = pe[j] - mm[j];
            float t1  = xm * rr[j];
            float t2v = t1 * gg[j];
            float t3v = t2v + bb[j];
            float t = fmaxf(t3v, 0.0f);
            en[j] = em[j] + t;
            sg[j] = 1.0f / (1.0f + expf(-en[j]));
          }
          *(f32x4*)(np + i*4) = en;
          *(f32x4*)&sA[sa_r][sa_k + i*4] = sg;
        }
      }
      __syncthreads();

      #pragma unroll
      for (int q = 0; q < 8; ++q){
        f32x4 b0 = *(const f32x4*)&sW[4*q + 0][c0];
        f32x4 b1 = *(const f32x4*)&sW[4*q + 1][c0];
        f32x4 b2 = *(const f32x4*)&sW[4*q + 2][c0];
        f32x4 b3 = *(const f32x4*)&sW[4*q + 3][c0];
        #pragma unroll
        for (int r = 0; r < 16; ++r){
          f32x4 a = *(const f32x4*)&sA[r0 + r][4*q];
          #pragma unroll
          for (int j = 0; j < 4; ++j){
            float t = acc[r][j];
            t = fmaf(a[0], b0[j], t); t = fmaf(a[1], b1[j], t);
            t = fmaf(a[2], b2[j], t); t = fmaf(a[3], b3[j], t);
            acc[r][j] = t;
          }
        }
      }
      __syncthreads();
    }

    #pragma unroll
    for (int r = 0; r < 16; ++r){
      int row = rowBase + r0 + r;
      f32x4 o;
      #pragma unroll
      for (int j = 0; j < 4; ++j) o[j] = acc[r][j];
      *(f32x4*)&sigmaOut[(size_t)row * DD + c0] = o;
    }
  }
}

// ---------------- CSR build: bucket edges by dst ----------------
__global__ void hist_k(const int* __restrict__ dst, int NE, int* __restrict__ counts){
  int i = blockIdx.x * blockDim.x + threadIdx.x;
  if (i < NE) atomicAdd(&counts[dst[i]], 1);
}

__global__ __launch_bounds__(1024, 1) void scan_k(const int* __restrict__ counts, int NN,
                                                  int* __restrict__ rowStart, int* __restrict__ cursor){
  __shared__ int part[1024];
  const int T = 1024, t = threadIdx.x;
  const int chunk = (NN + T - 1) / T;
  const int lo = t * chunk;
  const int hi = (lo + chunk < NN) ? lo + chunk : NN;
  int s = 0;
  for (int i = lo; i < hi; ++i) s += counts[i];
  part[t] = s;
  __syncthreads();
  for (int off = 1; off < T; off <<= 1){
    int v = (t >= off) ? part[t - off] : 0;
    __syncthreads();
    part[t] += v;
    __syncthreads();
  }
  int run = (t == 0) ? 0 : part[t - 1];
  for (int i = lo; i < hi; ++i){ rowStart[i] = run; cursor[i] = run; run += counts[i]; }
  if (t == T - 1) rowStart[NN] = run;
}

__global__ void place_k(const int* __restrict__ dst, int NE,
                        int* __restrict__ cursor, int* __restrict__ edgeIdx){
  int i = blockIdx.x * blockDim.x + threadIdx.x;
  if (i < NE){ int p = atomicAdd(&cursor[dst[i]], 1); edgeIdx[p] = i; }
}

// ---------------- gather-reduce: den/num from dense sigma, bucket order ------
__global__ __launch_bounds__(256, 4) void gather_k(
    const float* __restrict__ sigma, const float* __restrict__ Vh,
    const int* __restrict__ rowStart, const int* __restrict__ edgeIdx,
    const int* __restrict__ srcArr,
    const float* __restrict__ Uh, float* __restrict__ preH, int NN)
{
  const int lane = threadIdx.x & 63, wv = threadIdx.x >> 6;
  for (int node = blockIdx.x * 4 + wv; node < NN; node += gridDim.x * 4){
    const int beg = rowStart[node], end = rowStart[node + 1];
    float den0 = 0.f, den1 = 0.f, num0 = 0.f, num1 = 0.f;
    for (int eb = beg; eb < end; eb += 8){
      const int nE = end - eb;
      float sg0[8], sg1[8], vh0[8], vh1[8];
      #pragma unroll
      for (int q = 0; q < 8; ++q){
        if (q < nE){
          int eid = edgeIdx[eb + q];
          int s = srcArr[eid];
          sg0[q] = sigma[(size_t)eid * DD + lane];
          sg1[q] = sigma[(size_t)eid * DD + 64 + lane];
          vh0[q] = Vh[(size_t)s * DD + lane];
          vh1[q] = Vh[(size_t)s * DD + 64 + lane];
        } else { sg0[q] = 0.f; sg1[q] = 0.f; vh0[q] = 0.f; vh1[q] = 0.f; }
      }
      #pragma unroll
      for (int q = 0; q < 8; ++q){
        den0 += sg0[q]; den1 += sg1[q];
        num0 = fmaf(sg0[q], vh0[q], num0);
        num1 = fmaf(sg1[q], vh1[q], num1);
      }
    }
    const size_t b = (size_t)node * DD;
    preH[b + lane]      = Uh[b + lane]      + num0 / (den0 + 1e-5f);
    preH[b + 64 + lane] = Uh[b + 64 + lane] + num1 / (den1 + 1e-5f);
  }
}

// e-BN params: f64 stats -> f32 mean and f32 rsqrt
__global__ void finalizeE_k(const double* __restrict__ sum, const double* __restrict__ sumsq,
                            double M, float* __restrict__ mF, float* __restrict__ rF)
{
  int c = threadIdx.x;
  double m = sum[c] / M;
  double v = sumsq[c] / M - m * m;
  float vf = (float)v;
  mF[c] = (float)m;
  rF[c] = 1.0f / sqrtf(vf + 1e-5f);
}

// column stats (f32 in, f64 accum)
__global__ void stats64_k(const float* __restrict__ X, int M,
                          double* __restrict__ sum, double* __restrict__ sumsq)
{
  const int col = threadIdx.x & 127;
  const int half = threadIdx.x >> 7;
  double s = 0.0, q = 0.0;
  for (int r = blockIdx.x * 2 + half; r < M; r += gridDim.x * 2){
    double v = (double)X[(size_t)r * DD + col];
    s += v; q += v * v;
  }
  __shared__ double sS[256], sQ[256];
  sS[threadIdx.x] = s; sQ[threadIdx.x] = q;
  __syncthreads();
  if (half == 0){
    atomicAdd(&sum[col],   sS[col] + sS[col + 128]);
    atomicAdd(&sumsq[col], sQ[col] + sQ[col + 128]);
  }
}

__global__ void finalize64_k(const double* __restrict__ sum, const double* __restrict__ sumsq,
                             double M, const float* __restrict__ gamma, const float* __restrict__ beta,
                             double* __restrict__ scale, double* __restrict__ shift)
{
  int c = threadIdx.x;
  double m = sum[c] / M;
  double var = sumsq[c] / M - m * m;
  double sc = (double)gamma[c] / sqrt(var + 1e-5);
  scale[c] = sc;
  shift[c] = (double)beta[c] - m * sc;
}

// ---------------- split-bf16 MFMA GEMM: h_new = h@Wemb_n + relu(bn(pre_h)) ----
__global__ __launch_bounds__(256, 2) void hfinal_mfma_k(
    const float* __restrict__ X, const float* __restrict__ W,
    float* __restrict__ Y, int M, int rowTiles,
    const float* __restrict__ preH,
    const double* __restrict__ hSc, const double* __restrict__ hSh)
{
  const int tid = threadIdx.x;
  const int lane = tid & 63;
  const int wv = tid >> 6;
  const int l15 = lane & 15;
  const int lg = lane >> 4;
  const int colBase = blockIdx.y * 64;

  __shared__ short sW[2][64][136];
  for (int t = tid; t < 64 * 128; t += 256){
    int k = t >> 6, nl = t & 63;
    float w = W[k * DD + colBase + nl];
    short hi = f2bf(w);
    sW[0][nl][k] = hi;
    sW[1][nl][k] = f2bf(w - bf2f(hi));
  }
  __syncthreads();

  bf16x8 Bhi[4][4], Blo[4][4];
  #pragma unroll
  for (int ct = 0; ct < 4; ++ct)
    #pragma unroll
    for (int ks = 0; ks < 4; ++ks){
      Bhi[ct][ks] = *(const bf16x8*)&sW[0][ct*16 + l15][ks*32 + lg*8];
      Blo[ct][ks] = *(const bf16x8*)&sW[1][ct*16 + l15][ks*32 + lg*8];
    }

  for (int rt = blockIdx.x; rt < rowTiles; rt += gridDim.x){
    int arow = rt * 64 + wv * 16 + l15;
    if (arow >= M) arow = M - 1;
    const f32x4* xr = (const f32x4*)(X + (size_t)arow * DD);

    bf16x8 Ahi[4], Alo[4];
    #pragma unroll
    for (int ks = 0; ks < 4; ++ks){
      f32x4 a0 = xr[ks*8 + lg*2];
      f32x4 a1 = xr[ks*8 + lg*2 + 1];
      float av[8];
      #pragma unroll
      for (int j = 0; j < 4; ++j){ av[j] = a0[j]; av[4+j] = a1[j]; }
      #pragma unroll
      for (int j = 0; j < 8; ++j){
        short hi = f2bf(av[j]);
        Ahi[ks][j] = hi;
        Alo[ks][j] = f2bf(av[j] - bf2f(hi));
      }
    }

    f32x4 acc[4];
    #pragma unroll
    for (int ct = 0; ct < 4; ++ct) acc[ct] = (f32x4){0.f, 0.f, 0.f, 0.f};
    #pragma unroll
    for (int ct = 0; ct < 4; ++ct)
      #pragma unroll
      for (int ks = 0; ks < 4; ++ks){
        acc[ct] = __builtin_amdgcn_mfma_f32_16x16x32_bf16(Ahi[ks], Bhi[ct][ks], acc[ct], 0, 0, 0);
        acc[ct] = __builtin_amdgcn_mfma_f32_16x16x32_bf16(Ahi[ks], Blo[ct][ks], acc[ct], 0, 0, 0);
        acc[ct] = __builtin_amdgcn_mfma_f32_16x16x32_bf16(Alo[ks], Bhi[ct][ks], acc[ct], 0, 0, 0);
      }

    const int r0 = rt * 64 + wv * 16 + lg * 4;
    #pragma unroll
    for (int reg = 0; reg < 4; ++reg){
      int r = r0 + reg;
      if (r < M){
        #pragma unroll
        for (int ct = 0; ct < 4; ++ct){
          int c = colBase + ct*16 + l15;
          double t = (double)preH[(size_t)r * DD + c] * hSc[c] + hSh[c];
          float tv = t > 0.0 ? (float)t : 0.0f;
          Y[(size_t)r * DD + c] = acc[ct][reg] + tv;
        }
      }
    }
  }
}

extern "C" void kernel_launch(void* const* d_in, const int* in_sizes, int n_in,
                              void* d_out, int out_size, void* d_ws, size_t ws_size,
                              hipStream_t stream)
{
  const float* h  = (const float*)d_in[0];
  const float* e  = (const float*)d_in[1];
  const int* src  = (const int*)d_in[2];
  const int* dst  = (const int*)d_in[3];
  const float* Wemb_n   = (const float*)d_in[4];
  const float* Wemb_e   = (const float*)d_in[5];
  const float* Wemb_eta = (const float*)d_in[6];
  const float* Uw  = (const float*)d_in[7];  const float* Ub  = (const float*)d_in[8];
  const float* Vw  = (const float*)d_in[9];  const float* Vb  = (const float*)d_in[10];
  const float* W1w = (const float*)d_in[11]; const float* W1b = (const float*)d_in[12];
  const float* W2w = (const float*)d_in[13]; const float* W2b = (const float*)d_in[14];
  const float* W3w = (const float*)d_in[15]; const float* W3b = (const float*)d_in[16];
  const float* h_gamma = (const float*)d_in[17]; const float* h_beta = (const float*)d_in[18];
  const float* e_gamma = (const float*)d_in[19]; const float* e_beta = (const float*)d_in[20];

  const int NN = in_sizes[0] / DD;   // 50000
  const int NE = in_sizes[2];        // 400000

  // workspace: W2h | W3h | Vh | embSig (e_emb -> sigma, shared) | stats | mF,rF | CSR
  char* wsp = (char*)d_ws;
  float* W2h    = (float*)wsp;  wsp += (size_t)NN * DD * sizeof(float);
  float* W3h    = (float*)wsp;  wsp += (size_t)NN * DD * sizeof(float);
  float* Vh     = (float*)wsp;  wsp += (size_t)NN * DD * sizeof(float);
  float* embSig = (float*)wsp;  wsp += (size_t)NE * DD * sizeof(float);
  double* stats = (double*)wsp; wsp += 6 * DD * sizeof(double);
  double* eSum = stats;        double* eSumSq = stats + DD;
  double* hSum = stats + 2*DD; double* hSumSq = stats + 3*DD;
  double* hScale = stats + 4*DD; double* hShift = stats + 5*DD;
  float* mF = (float*)wsp;   wsp += DD * sizeof(float);
  float* rF = (float*)wsp;   wsp += DD * sizeof(float);
  int* counts   = (int*)wsp; wsp += (size_t)NN * sizeof(int);
  int* rowStart = (int*)wsp; wsp += ((size_t)NN + 1) * sizeof(int);
  int* cursor   = (int*)wsp; wsp += (size_t)NN * sizeof(int);
  int* edgeIdx  = (int*)wsp; wsp += (size_t)NE * sizeof(int);

  float* h_new_out = (float*)d_out;                    // Uh -> pre_h -> h_new
  float* e_out     = (float*)d_out + (size_t)NN * DD;  // pre_e -> e_new

  const int tN = (NN + 127) / 128;    // 391
  const int tE = (NE + 127) / 128;    // 3125 (exact)
  const int rtN64 = (NN + 63) / 64;
  dim3 blk256(256);

  hipMemsetAsync(stats, 0, (size_t)4 * DD * sizeof(double), stream);
  hipMemsetAsync(counts, 0, (size_t)NN * sizeof(int), stream);

  // CSR build
  hist_k<<<(NE + 255) / 256, blk256, 0, stream>>>(dst, NE, counts);
  scan_k<<<1, 1024, 0, stream>>>(counts, NN, rowStart, cursor);
  place_k<<<(NE + 255) / 256, blk256, 0, stream>>>(dst, NE, cursor, edgeIdx);

  // merged node GEMMs: one launch, 4x fill (y selects weight set)
  node4_k<<<dim3(tN, 4), blk256, 0, stream>>>(h,
      Uw, Ub, h_new_out,
      Vw, Vb, Vh,
      W2w, W2b, W2h,
      W3w, W3b, W3h,
      NN, tN);

  // pre_e = ((e@W1 + W1b) + W2h[src]) + W3h[dst] -> e_out; fused f64 stats
  fgemmE1_k<<<1024, blk256, 0, stream>>>(e, W1w, W1b, e_out, NE, tE,
      src, dst, W2h, W3h, eSum, eSumSq);

  finalizeE_k<<<1, 128, 0, stream>>>(eSum, eSumSq, (double)NE, mF, rF);

  // e_emb = e @ Wemb_e -> embSig
  fgemm0_k<<<1024, blk256, 0, stream>>>(e, Wemb_e, nullptr, embSig, NE, tE);

  // fused: e_new = e_emb + relu(bn(pre_e)) (-> e_out), sigma = sigmoid(e_new)@Weta
  // sigma written over embSig (write-after-read per tile)
  psgemm_k<<<1024, blk256, 0, stream>>>(e_out, embSig, Wemb_eta, e_out, embSig,
      mF, rF, e_gamma, e_beta, NE, tE);

  // bucket-order gather-reduce: pre_h = Uh + num/(den+1e-5)  (in place over d_out)
  gather_k<<<(NN + 3) / 4, blk256, 0, stream>>>(embSig, Vh, rowStart, edgeIdx, src,
      h_new_out, h_new_out, NN);

  stats64_k<<<512, blk256, 0, stream>>>(h_new_out, NN, hSum, hSumSq);
  finalize64_k<<<1, 128, 0, stream>>>(hSum, hSumSq, (double)NN, h_gamma, h_beta, hScale, hShift);

  // h_new = h@Wemb_n + relu(bn(pre_h))  (MFMA; post-division path)
  hfinal_mfma_k<<<dim3(rtN64, 2), blk256, 0, stream>>>(h, Wemb_n, h_new_out, NN, rtN64,
      h_new_out, hScale, hShift);
}